// Round 7
// baseline (5405.431 us; speedup 1.0000x reference)
//
#include <hip/hip_runtime.h>
#include <cstdint>
#include <cstddef>

// ---------------------------------------------------------------------------
// GConvGRU (ChebConv K=3, 2 layers) + readout, for MI355X.
// R15 (8.2->6.8ms): gateA -> MFMA register GEMM.
// R16 (6.8->6.0ms): basis intermediates fp16-only; dual-gather spmm.
// R17 (6.0->5.5ms): all side-streams fp16.
// R18 (~neutral): L0 x-basis hoisted+batched; 12 concurrent slabs thrashed
//   per-XCD L2 (352MB FETCH @3.3TB/s).
// R19 (5.49->5.37): GRU H state fp16-only. absmax bit-pinned at 0.0039.
// R20 (this): gathers are L2-MISS-bound (private 4MB per-XCD L2 can't hold
//   12.8MB tables). Make them L2-resident by XCD-pinning via the linear
//   blockIdx%8 round-robin:
//   (a) spmm32x: slab->XCD pinned (slabs 0-7 one/XCD, 8-11 two XCDs each),
//       per-XCD WS 3.2MB. 2 launches per basis step.
//   (b) spmm128c (HR chains, x2/ts): HRbh stored CHUNK-major [4][N][32]
//       (chunk=batch); chunk->XCD-pair pinned; writes th1h row-major
//       (gateB's integrated gather needs full rows). gateA writes HRbh
//       chunk-major; gateB zih read re-indexed.
//   Arithmetic bit-identical => absmax stays 0.00390625.
//   Predicted: 5.37 -> ~4.9ms (neutral if XCD heuristic wrong).
// ---------------------------------------------------------------------------

typedef _Float16 half4 __attribute__((ext_vector_type(4)));
typedef _Float16 half8_t __attribute__((ext_vector_type(8)));
typedef float f32x4 __attribute__((ext_vector_type(4)));

__device__ __forceinline__ float sigmoidf_(float x){ return 1.f/(1.f+__expf(-x)); }

// ---------------- preprocessing ----------------

__global__ void detect_kernel(const unsigned* __restrict__ buf, int ndw, int* flag){
  int i = blockIdx.x*blockDim.x + threadIdx.x;
  int j = 2*i + 1;
  if (j < ndw && buf[j] != 0u) atomicOr(flag, 1);   // flag=1 -> int32
}

__global__ void convert_kernel(const void* __restrict__ eidx, const float* __restrict__ w,
                               int E, const int* __restrict__ flag,
                               int* __restrict__ row32, int* __restrict__ col32,
                               float* __restrict__ deg, int* __restrict__ cnt){
  int e = blockIdx.x*blockDim.x + threadIdx.x;
  if (e >= E) return;
  int r, c;
  if (*flag){ const int* p = (const int*)eidx; r = p[e]; c = p[E+e]; }
  else { const long long* p = (const long long*)eidx; r = (int)p[e]; c = (int)p[(size_t)E+e]; }
  row32[e] = r; col32[e] = c;
  atomicAdd(deg + r, w[e]);
  atomicAdd(cnt + c, 1);
}

__global__ void node_prep_kernel(const float* __restrict__ deg, float* __restrict__ dinv,
                                 float* __restrict__ dg, int N){
  int n = blockIdx.x*blockDim.x + threadIdx.x;
  if (n >= N) return;
  float d = deg[n];
  if (d > 0.f){ dinv[n] = rsqrtf(d); dg[n] = 0.f; }
  else        { dinv[n] = 0.f;       dg[n] = -1.f; }
}

// Exclusive scan of PADDED counts ((cnt+7)&~7) -> ptr[N+1]. 1 block, 1024 thr.
__global__ void scan_kernel(const int* __restrict__ cnt, int* __restrict__ ptrout, int N){
  __shared__ int s[1024];
  int t = threadIdx.x;
  int chunk = (N + 1023) / 1024;
  int a0 = t*chunk, a1 = min(N, a0 + chunk);
  int sum = 0;
  for (int i = a0; i < a1; ++i) sum += (cnt[i]+7)&~7;
  s[t] = sum; __syncthreads();
  for (int off = 1; off < 1024; off <<= 1){
    int v = (t >= off) ? s[t-off] : 0;
    __syncthreads();
    s[t] += v;
    __syncthreads();
  }
  int run = (t == 0) ? 0 : s[t-1];
  for (int i = a0; i < a1; ++i){ ptrout[i] = run; run += (cnt[i]+7)&~7; }
  if (t == 1023) ptrout[N] = s[1023];
}

__global__ void fill_kernel(const int* __restrict__ row32, const int* __restrict__ col32,
                            const float* __restrict__ w, const float* __restrict__ dinv,
                            const int* __restrict__ ptrv, int* __restrict__ cnt2,
                            int* __restrict__ srcs, float* __restrict__ vals, int E){
  int e = blockIdx.x*blockDim.x + threadIdx.x;
  if (e >= E) return;
  int r = row32[e], c = col32[e];
  int p = ptrv[c] + atomicAdd(cnt2 + c, 1);
  srcs[p] = r;
  vals[p] = -w[e] * dinv[r] * dinv[c];
}

// Pad slots gather (src=0, val=0): bit-identical arithmetic, L2-hot row.
__global__ void pad_kernel(const int* __restrict__ cnt, const int* __restrict__ ptrv,
                           int* __restrict__ srcs, float* __restrict__ vals, int N){
  int n = blockIdx.x*blockDim.x + threadIdx.x;
  if (n >= N) return;
  int base = ptrv[n];
  int real = cnt[n];
  int padded = ptrv[n+1] - base;
  for (int j = real; j < padded; ++j){ srcs[base+j] = 0; vals[base+j] = 0.f; }
}

// ---------------- chunked SpMM: th1 = L(HRb), XCD-pinned feature chunks ----
// xc chunk-major [4][N][8] half4 (chunk=batch, 3.2MB each -> one XCD pair's
// L2). y written ROW-major [N][32] half4 (gateB gathers full rows).
__global__ __launch_bounds__(256) void spmm128c_kernel(
    const int* __restrict__ ptrv, const int* __restrict__ srcs, const float* __restrict__ vals,
    const float* __restrict__ dg, const half4* __restrict__ xc,
    half4* __restrict__ y, int N){
  int i = blockIdx.x;
  int xcd = i & 7;
  int c   = xcd >> 1;                 // chunk -> XCD pair (id%8 round-robin)
  int j   = (i >> 3)*2 + (xcd & 1);   // block index within chunk
  int t = threadIdx.x;
  int g = t >> 3, lane = t & 7;
  int node = j*32 + g;
  if (node >= N) return;
  const half4* xs = xc + (size_t)c * N * 8;
  int e0 = ptrv[node], e1 = ptrv[node+1];
  float4 acc = make_float4(0.f,0.f,0.f,0.f);
  for (int eb = e0; eb < e1; eb += 8){
    int jj = eb + lane;
    int s = srcs[jj]; float v = vals[jj];
    #pragma unroll
    for (int q = 0; q < 8; ++q){
      int   sq = __shfl(s, q, 8);
      float vq = __shfl(v, q, 8);
      half4 hv = xs[(size_t)sq*8 + lane];
      acc.x = fmaf(vq, (float)hv.x, acc.x);
      acc.y = fmaf(vq, (float)hv.y, acc.y);
      acc.z = fmaf(vq, (float)hv.z, acc.z);
      acc.w = fmaf(vq, (float)hv.w, acc.w);
    }
  }
  float dgn = dg[node];
  half4 xi = xs[(size_t)node*8 + lane];
  half4 hr;
  hr.x = (_Float16)(acc.x + dgn*(float)xi.x);
  hr.y = (_Float16)(acc.y + dgn*(float)xi.y);
  hr.z = (_Float16)(acc.z + dgn*(float)xi.z);
  hr.w = (_Float16)(acc.w + dgn*(float)xi.w);
  y[(size_t)node*32 + c*8 + lane] = hr;
}

// ---------------- dual SpMM F=128: two tables, one edge-list read ----------
// ya = a*(A xa + diag*xa) + b*za ; same for b-side. za/zb fp16 (may be null).
__global__ __launch_bounds__(256) void spmm_dual_kernel(
    const int* __restrict__ ptrv, const int* __restrict__ srcs, const float* __restrict__ vals,
    const float* __restrict__ dg,
    const half4* __restrict__ xa, const half4* __restrict__ xb,
    const half4* __restrict__ za, const half4* __restrict__ zb,
    half4* __restrict__ ya, half4* __restrict__ yb, int N, float alpha, float beta){
  int t = threadIdx.x;
  int g = t >> 5, lane = t & 31;
  int node = blockIdx.x*8 + g;
  if (node >= N) return;
  int e0 = ptrv[node], e1 = ptrv[node+1];
  float4 aa = make_float4(0.f,0.f,0.f,0.f);
  float4 ab = make_float4(0.f,0.f,0.f,0.f);
  for (int eb = e0; eb < e1; eb += 8){
    int j = eb + (lane & 7);
    int s = srcs[j]; float v = vals[j];
    #pragma unroll
    for (int q = 0; q < 8; ++q){
      int   sq = __shfl(s, q, 32);
      float vq = __shfl(v, q, 32);
      half4 ha = xa[(size_t)sq*32 + lane];
      half4 hb = xb[(size_t)sq*32 + lane];
      aa.x = fmaf(vq, (float)ha.x, aa.x);
      aa.y = fmaf(vq, (float)ha.y, aa.y);
      aa.z = fmaf(vq, (float)ha.z, aa.z);
      aa.w = fmaf(vq, (float)ha.w, aa.w);
      ab.x = fmaf(vq, (float)hb.x, ab.x);
      ab.y = fmaf(vq, (float)hb.y, ab.y);
      ab.z = fmaf(vq, (float)hb.z, ab.z);
      ab.w = fmaf(vq, (float)hb.w, ab.w);
    }
  }
  size_t ii = (size_t)node*32 + lane;
  float dgn = dg[node];
  half4 xia = xa[ii], xib = xb[ii];
  float4 ra, rb;
  ra.x = alpha*(aa.x + dgn*(float)xia.x);
  ra.y = alpha*(aa.y + dgn*(float)xia.y);
  ra.z = alpha*(aa.z + dgn*(float)xia.z);
  ra.w = alpha*(aa.w + dgn*(float)xia.w);
  rb.x = alpha*(ab.x + dgn*(float)xib.x);
  rb.y = alpha*(ab.y + dgn*(float)xib.y);
  rb.z = alpha*(ab.z + dgn*(float)xib.z);
  rb.w = alpha*(ab.w + dgn*(float)xib.w);
  if (za){
    half4 zva = za[ii];
    half4 zvb = zb[ii];
    ra.x = fmaf(beta, (float)zva.x, ra.x); ra.y = fmaf(beta, (float)zva.y, ra.y);
    ra.z = fmaf(beta, (float)zva.z, ra.z); ra.w = fmaf(beta, (float)zva.w, ra.w);
    rb.x = fmaf(beta, (float)zvb.x, rb.x); rb.y = fmaf(beta, (float)zvb.y, rb.y);
    rb.z = fmaf(beta, (float)zvb.z, rb.z); rb.w = fmaf(beta, (float)zvb.w, rb.w);
  }
  half4 hra, hrb;
  hra.x = (_Float16)ra.x; hra.y = (_Float16)ra.y; hra.z = (_Float16)ra.z; hra.w = (_Float16)ra.w;
  hrb.x = (_Float16)rb.x; hrb.y = (_Float16)rb.y; hrb.z = (_Float16)rb.z; hrb.w = (_Float16)rb.w;
  ya[ii] = hra;
  yb[ii] = hrb;
}

// ---------------- SpMM F=32, fp16, XCD-PINNED slabs -----------------------
// two_per_xcd=0: slabs slab0..slab0+7, one per XCD (id%8).
// two_per_xcd=1: slabs slab0..slab0+3, one per XCD pair.
__global__ __launch_bounds__(256) void spmm32x_kernel(
    const int* __restrict__ ptrv, const int* __restrict__ srcs, const float* __restrict__ vals,
    const float* __restrict__ dg, const half4* __restrict__ xh, const half4* __restrict__ z,
    half4* __restrict__ yh, int N, float alpha, float beta,
    int slab0, int two_per_xcd){
  int i = blockIdx.x;
  int xcd = i & 7;
  int slab, j;
  if (two_per_xcd){ slab = slab0 + (xcd >> 1); j = (i >> 3)*2 + (xcd & 1); }
  else            { slab = slab0 + xcd;        j = i >> 3; }
  size_t soff = (size_t)slab * N * 8;   // half4 units per slab
  const half4* xs = xh + soff;
  half4*       ys = yh + soff;
  int t = threadIdx.x;
  int g = t >> 3, lane = t & 7;
  int node = j*32 + g;
  if (node >= N) return;
  int e0 = ptrv[node], e1 = ptrv[node+1];
  float4 acc = make_float4(0.f,0.f,0.f,0.f);
  for (int eb = e0; eb < e1; eb += 8){
    int jj = eb + lane;
    int s = srcs[jj]; float v = vals[jj];
    #pragma unroll
    for (int q = 0; q < 8; ++q){
      int   sq = __shfl(s, q, 8);
      float vq = __shfl(v, q, 8);
      half4 hv = xs[(size_t)sq*8 + lane];
      acc.x = fmaf(vq, (float)hv.x, acc.x);
      acc.y = fmaf(vq, (float)hv.y, acc.y);
      acc.z = fmaf(vq, (float)hv.z, acc.z);
      acc.w = fmaf(vq, (float)hv.w, acc.w);
    }
  }
  size_t ii = (size_t)node*8 + lane;
  float dgn = dg[node];
  half4 xi = xs[ii];
  float4 r;
  r.x = alpha*(acc.x + dgn*(float)xi.x);
  r.y = alpha*(acc.y + dgn*(float)xi.y);
  r.z = alpha*(acc.z + dgn*(float)xi.z);
  r.w = alpha*(acc.w + dgn*(float)xi.w);
  if (z){
    half4 zi = (z + soff)[ii];
    r.x = fmaf(beta, (float)zi.x, r.x);
    r.y = fmaf(beta, (float)zi.y, r.y);
    r.z = fmaf(beta, (float)zi.z, r.z);
    r.w = fmaf(beta, (float)zi.w, r.w);
  }
  half4 hr;
  hr.x = (_Float16)r.x; hr.y = (_Float16)r.y; hr.z = (_Float16)r.z; hr.w = (_Float16)r.w;
  ys[ii] = hr;
}

// ---------------- fused: th2 = 2*(L th1) - HRb  +  gateB GRU update --------
// All streams fp16 including GRU state. HRbh is CHUNK-major [4][N][8] half4.
__global__ __launch_bounds__(256) void spmm_gateB_kernel(
    const int* __restrict__ ptrv, const int* __restrict__ srcs, const float* __restrict__ vals,
    const float* __restrict__ dg, const half4* __restrict__ th1h,
    const half4* __restrict__ HRc,
    const float* __restrict__ Whh, const float* __restrict__ bhh,
    const half4* __restrict__ Zh, const half4* __restrict__ gx2h,
    half4* __restrict__ Hh, int N){
  __shared__ _Float16 sp[8][3][128];
  __shared__ float sW[3072];
  int t = threadIdx.x;
  int g = t >> 5, lane = t & 31;
  int node = blockIdx.x*8 + g;
  bool valid = (node < N);
  if (!valid) node = N-1;
  for (int idx = t; idx < 3072; idx += 256) sW[idx] = Whh[idx];
  size_t ii = (size_t)node*32 + lane;
  // HRbh own row, chunk-major: chunk = lane>>3, feat quad = lane&7
  size_t iiz = (size_t)(lane >> 3)*(size_t)N*8 + (size_t)node*8 + (lane & 7);
  half4 Zvh  = Zh[ii];
  half4 Gxh  = gx2h[ii];
  half4 Holdh = Hh[ii];
  half4 zih  = HRc[iiz];
  int e0 = ptrv[node], e1 = ptrv[node+1];
  float4 acc = make_float4(0.f,0.f,0.f,0.f);
  for (int eb = e0; eb < e1; eb += 8){
    int j = eb + (lane & 7);
    int s = srcs[j]; float v = vals[j];
    #pragma unroll
    for (int q = 0; q < 8; ++q){
      int   sq = __shfl(s, q, 32);
      float vq = __shfl(v, q, 32);
      half4 hv = th1h[(size_t)sq*32 + lane];
      acc.x = fmaf(vq, (float)hv.x, acc.x);
      acc.y = fmaf(vq, (float)hv.y, acc.y);
      acc.z = fmaf(vq, (float)hv.z, acc.z);
      acc.w = fmaf(vq, (float)hv.w, acc.w);
    }
  }
  float dgn = dg[node];
  half4 xih = th1h[ii];
  half4 p2h;
  p2h.x = (_Float16)(2.f*(acc.x + dgn*(float)xih.x) - (float)zih.x);
  p2h.y = (_Float16)(2.f*(acc.y + dgn*(float)xih.y) - (float)zih.y);
  p2h.z = (_Float16)(2.f*(acc.z + dgn*(float)xih.z) - (float)zih.z);
  p2h.w = (_Float16)(2.f*(acc.w + dgn*(float)xih.w) - (float)zih.w);
  ((half4*)&sp[g][0][0])[lane] = zih;
  ((half4*)&sp[g][1][0])[lane] = xih;
  ((half4*)&sp[g][2][0])[lane] = p2h;
  __syncthreads();
  const float4* W4 = (const float4*)sW;
  float4 bv = ((const float4*)bhh)[lane & 7];
  float gh0 = bv.x, gh1 = bv.y, gh2 = bv.z, gh3 = bv.w;
  #pragma unroll 1
  for (int k = 0; k < 3; ++k){
    const _Float16* pk = &sp[g][k][(lane >> 3)*32];
    #pragma unroll
    for (int o = 0; o < 32; o += 4){
      half4 pv = *reinterpret_cast<const half4*>(pk + o);
      #pragma unroll
      for (int oo = 0; oo < 4; ++oo){
        float p = (float)pv[oo];
        float4 wv = W4[k*256 + (o+oo)*8 + (lane & 7)];
        gh0 = fmaf(p, wv.x, gh0);
        gh1 = fmaf(p, wv.y, gh1);
        gh2 = fmaf(p, wv.z, gh2);
        gh3 = fmaf(p, wv.w, gh3);
      }
    }
  }
  if (valid){
    half4 hh;
    float Ht, Z;
    Z = (float)Zvh.x; Ht = tanhf((float)Gxh.x + gh0); hh.x = (_Float16)(Z*(float)Holdh.x + (1.f - Z)*Ht);
    Z = (float)Zvh.y; Ht = tanhf((float)Gxh.y + gh1); hh.y = (_Float16)(Z*(float)Holdh.y + (1.f - Z)*Ht);
    Z = (float)Zvh.z; Ht = tanhf((float)Gxh.z + gh2); hh.z = (_Float16)(Z*(float)Holdh.z + (1.f - Z)*Ht);
    Z = (float)Zvh.w; Ht = tanhf((float)Gxh.w + gh3); hh.w = (_Float16)(Z*(float)Holdh.w + (1.f - Z)*Ht);
    Hh[ii] = hh;
  }
}

// ---------------- transpose layer-0 input, ALL timesteps (-> fp16 slabs) ---
__global__ void transpose_all_kernel(const float* __restrict__ in, _Float16* __restrict__ out,
                                     int N){
  int idx = blockIdx.x*blockDim.x + threadIdx.x;   // over N*32
  int t = blockIdx.y;                               // timestep slab
  if (idx >= N*32) return;
  int n = idx >> 5; int r = idx & 31; int b = r >> 3; int i = r & 7;
  out[(size_t)t*N*32 + idx] = (_Float16)in[(((size_t)b*12 + t)*N + n)*8 + i];
}

// ---------------- gateA: MFMA GEMM -----------------------------------------
// Weight pack to f16 MFMA B-fragment layout (k = 8*(lane>>4)+j, col = lane&15,
// SAME mapping used when building A, so any HW k-permutation cancels).
__global__ void prep_weights_kernel(const float* __restrict__ Wx0, const float* __restrict__ Wx1,
                                    const float* __restrict__ Wh0, const float* __restrict__ Wh1,
                                    _Float16* __restrict__ bx8, _Float16* __restrict__ bx32,
                                    _Float16* __restrict__ bh0f, _Float16* __restrict__ bh1f){
  int t0 = threadIdx.x;
  for (int idx = t0; idx < 9216; idx += 256){
    int j = idx & 7; int l = (idx>>3)&63; int tc = idx>>9;     // tc = t*3+c
    int tt = tc/3, c = tc - 3*tt;
    int out = tt*16 + (l&15); int g = out>>5; int o = out&31;
    int fin = 8*(l>>4)+j;
    bx32[idx] = (_Float16)Wx1[(((g*3+c)*32+fin)<<5)+o];
  }
  for (int idx = t0; idx < 3072; idx += 256){
    int j = idx & 7; int l = (idx>>3)&63; int tt = idx>>9;
    int out = tt*16 + (l&15); int g = out>>5; int o = out&31;
    int b = l>>4;
    bx8[idx] = (b < 3) ? (_Float16)Wx0[(((g*3+b)*8+j)<<5)+o] : (_Float16)0.f;
  }
  for (int idx = t0; idx < 6144; idx += 256){
    int j = idx & 7; int l = (idx>>3)&63; int tc = idx>>9;     // tc = u*3+c, u<4
    int u = tc/3, c = tc - 3*u;
    int out = u*16 + (l&15); int g = out>>5; int o = out&31;
    int fin = 8*(l>>4)+j;
    bh0f[idx] = (_Float16)Wh0[(((g*3+c)*32+fin)<<5)+o];
    bh1f[idx] = (_Float16)Wh1[(((g*3+c)*32+fin)<<5)+o];
  }
}

// Per wave: one 16-row tile x 160 output cols (10 C tiles), grid-stride over
// tiles with B resident in VGPRs. HRbh output is CHUNK-major [4][N][32].
template<int FIN>
__global__ __launch_bounds__(256) void gateA_mfma_kernel(
    const _Float16* __restrict__ x0h, const _Float16* __restrict__ x1h,
    const _Float16* __restrict__ x2h,                       // [M x FIN] halves
    const _Float16* __restrict__ h0h, const _Float16* __restrict__ h1h,
    const _Float16* __restrict__ h2h,                       // [M x 32] halves
    const _Float16* __restrict__ BX, const float* __restrict__ bx,
    const _Float16* __restrict__ BH, const float* __restrict__ bh,
    _Float16* __restrict__ Zh, _Float16* __restrict__ gx2h,
    _Float16* __restrict__ HRc, int M, int Nn, int ntiles){
  constexpr int NXC = (FIN == 32) ? 3 : 1;
  int t = threadIdx.x;
  int lane = t & 63, wv = t >> 6;
  int l15 = lane & 15, lhi = lane >> 4;

  half8_t Bxf[6*NXC], Bhf[12];
  {
    const half8_t* p = (const half8_t*)BX;
    #pragma unroll
    for (int i = 0; i < 6*NXC; ++i) Bxf[i] = p[i*64 + lane];
    const half8_t* q = (const half8_t*)BH;
    #pragma unroll
    for (int i = 0; i < 12; ++i) Bhf[i] = q[i*64 + lane];
  }
  float bz0 = bx[l15]    + bh[l15];
  float bz1 = bx[16+l15] + bh[16+l15];
  float br0 = bx[32+l15] + bh[32+l15];
  float br1 = bx[48+l15] + bh[48+l15];
  float b20 = bx[64+l15];
  float b21 = bx[80+l15];

  int wid = blockIdx.x*4 + wv;
  int nw  = gridDim.x*4;
  for (int tile = wid; tile < ntiles; tile += nw){
    int r0 = tile << 4;
    int rowa = r0 + l15; if (rowa >= M) rowa = M - 1;

    half8_t Ax[NXC], Ah[3];
    if constexpr (FIN == 32){
      const _Float16* xm[3] = {x0h, x1h, x2h};
      #pragma unroll
      for (int c = 0; c < 3; ++c)
        Ax[c] = *reinterpret_cast<const half8_t*>(xm[c] + (size_t)rowa*32 + 8*lhi);
    } else {
      if (lhi < 3){
        const _Float16* p = (lhi == 0) ? x0h : (lhi == 1) ? x1h : x2h;
        Ax[0] = *reinterpret_cast<const half8_t*>(p + (size_t)rowa*8);
      } else {
        #pragma unroll
        for (int j = 0; j < 8; ++j) Ax[0][j] = (_Float16)0.f;
      }
    }
    {
      const _Float16* hm[3] = {h0h, h1h, h2h};
      #pragma unroll
      for (int c = 0; c < 3; ++c)
        Ah[c] = *reinterpret_cast<const half8_t*>(hm[c] + (size_t)rowa*32 + 8*lhi);
    }

    f32x4 zv = {0.f, 0.f, 0.f, 0.f};
    f32x4 CX[6], CH[4];
    #pragma unroll
    for (int i = 0; i < 6; ++i) CX[i] = zv;
    #pragma unroll
    for (int i = 0; i < 4; ++i) CH[i] = zv;

    #pragma unroll
    for (int tt = 0; tt < 6; ++tt){
      #pragma unroll
      for (int c = 0; c < NXC; ++c)
        CX[tt] = __builtin_amdgcn_mfma_f32_16x16x32_f16(Ax[c], Bxf[tt*NXC+c], CX[tt], 0, 0, 0);
    }
    #pragma unroll
    for (int u = 0; u < 4; ++u){
      #pragma unroll
      for (int c = 0; c < 3; ++c)
        CH[u] = __builtin_amdgcn_mfma_f32_16x16x32_f16(Ah[c], Bhf[u*3+c], CH[u], 0, 0, 0);
    }

    // C/D layout: col = lane&15, row = 4*(lane>>4)+reg  [m89-verified]
    #pragma unroll
    for (int reg = 0; reg < 4; ++reg){
      int row = r0 + lhi*4 + reg;
      if (row < M){
        size_t i0 = (size_t)row*32 + l15;
        size_t i1 = i0 + 16;
        float Z0 = sigmoidf_(CX[0][reg] + CH[0][reg] + bz0);
        float Z1 = sigmoidf_(CX[1][reg] + CH[1][reg] + bz1);
        float R0 = sigmoidf_(CX[2][reg] + CH[2][reg] + br0);
        float R1 = sigmoidf_(CX[3][reg] + CH[3][reg] + br1);
        Zh[i0] = (_Float16)Z0; Zh[i1] = (_Float16)Z1;
        gx2h[i0] = (_Float16)(CX[4][reg] + b20);
        gx2h[i1] = (_Float16)(CX[5][reg] + b21);
        float hv0 = (float)h0h[i0]*R0, hv1 = (float)h0h[i1]*R1;
        // HRbh chunk-major: chunk = batch = row&3, node = row>>2
        size_t hc = (size_t)(row & 3)*((size_t)Nn*32) + (size_t)(row >> 2)*32 + l15;
        HRc[hc]      = (_Float16)hv0;
        HRc[hc + 16] = (_Float16)hv1;
      }
    }
  }
}

// ---------------- readout (fp16 H1) ----------------
__global__ void readout_kernel(const _Float16* __restrict__ H1, const float* __restrict__ muW,
                               const float* __restrict__ mub, const float* __restrict__ sgW,
                               const float* __restrict__ sgb, float* __restrict__ outp, int N){
  int idx = blockIdx.x*blockDim.x + threadIdx.x;   // over 4*N
  if (idx >= 4*N) return;
  int b = idx / N, n = idx - b*N;
  const _Float16* h = H1 + (size_t)n*128 + b*32;
  float m0 = mub[0], m1 = mub[1], s0 = sgb[0], s1 = sgb[1];
  #pragma unroll
  for (int o = 0; o < 32; ++o){
    float v = (float)h[o];
    m0 = fmaf(v, muW[o*2+0], m0);
    m1 = fmaf(v, muW[o*2+1], m1);
    s0 = fmaf(v, sgW[o*2+0], s0);
    s1 = fmaf(v, sgW[o*2+1], s1);
  }
  size_t base = (size_t)(b*N + n)*2;
  outp[base]   = sigmoidf_(m0);
  outp[base+1] = sigmoidf_(m1);
  size_t sb = (size_t)8*N + base;
  outp[sb]   = (s0 > 15.f) ? s0 : log1pf(__expf(s0));
  outp[sb+1] = (s1 > 15.f) ? s1 : log1pf(__expf(s1));
}

__global__ void mean_kernel(const _Float16* __restrict__ H1, float* __restrict__ mixsum, int N){
  int t = threadIdx.x;   // 128 = (b,o)
  int chunk = (N + gridDim.x - 1) / gridDim.x;
  int n0 = blockIdx.x*chunk, n1 = min(N, n0 + chunk);
  float acc = 0.f;
  for (int n = n0; n < n1; ++n) acc += (float)H1[(size_t)n*128 + t];
  atomicAdd(mixsum + t, acc);
}

__global__ void softmax_kernel(const float* __restrict__ mixsum, float* __restrict__ outp,
                               float invN){
  __shared__ float v[128];
  __shared__ float e[128];
  int t = threadIdx.x; int b = t >> 5;
  float m = mixsum[t]*invN;
  v[t] = m; __syncthreads();
  float mx = -1e30f;
  for (int o = 0; o < 32; ++o) mx = fmaxf(mx, v[b*32 + o]);
  float ex = __expf(m - mx);
  e[t] = ex; __syncthreads();
  float s = 0.f;
  for (int o = 0; o < 32; ++o) s += e[b*32 + o];
  outp[t] = ex / s;
}

// ---------------------------------------------------------------------------

extern "C" void kernel_launch(void* const* d_in, const int* in_sizes, int n_in,
                              void* d_out, int out_size, void* d_ws, size_t ws_size,
                              hipStream_t stream){
  const float* in0  = (const float*)d_in[0];
  const void*  eidx = d_in[1];
  const float* ew   = (const float*)d_in[2];
  const float* Wx0  = (const float*)d_in[3];
  const float* Wh0  = (const float*)d_in[4];
  const float* bx0  = (const float*)d_in[5];
  const float* bh0  = (const float*)d_in[6];
  const float* Wx1  = (const float*)d_in[7];
  const float* Wh1  = (const float*)d_in[8];
  const float* bx1  = (const float*)d_in[9];
  const float* bh1  = (const float*)d_in[10];
  const float* muW  = (const float*)d_in[11];
  const float* mub  = (const float*)d_in[12];
  const float* sgW  = (const float*)d_in[13];
  const float* sgb  = (const float*)d_in[14];
  float* outp = (float*)d_out;

  const int N = in_sizes[0] / (4*12*8);
  const int E = in_sizes[1] / 2;
  const int M = 4*N;
  const int EP = E + 8*N;        // padded-edge capacity

  // ---- carve workspace ----
  char* w = (char*)d_ws;
  size_t off = 0;
  auto alloc = [&](size_t bytes)->void*{
    void* p = w + off;
    off += (bytes + 255) & ~(size_t)255;
    return p;
  };
  int*   csr_src = (int*)  alloc((size_t)EP*4);
  float* csr_val = (float*)alloc((size_t)EP*4);
  int*   ptrv    = (int*)  alloc((size_t)(N+1)*4);
  int*   cnt     = (int*)  alloc((size_t)N*4);
  int*   cnt2    = (int*)  alloc((size_t)N*4);
  float* deg     = (float*)alloc((size_t)N*4);
  float* dinv    = (float*)alloc((size_t)N*4);
  float* dgv     = (float*)alloc((size_t)N*4);
  int*   flag    = (int*)  alloc(256);
  float* mixsum  = (float*)alloc(512);
  // fp16 gate buffers
  half4* Zh   = (half4*)alloc((size_t)N*128*2);
  half4* gx2h = (half4*)alloc((size_t)N*128*2);
  // fp16 L0 x-basis, batched over all 12 timesteps: [t][node][32] halves
  _Float16* xa0 = (_Float16*)alloc((size_t)12*N*32*2);
  _Float16* xa1 = (_Float16*)alloc((size_t)12*N*32*2);
  _Float16* xa2 = (_Float16*)alloc((size_t)12*N*32*2);
  // fp16 basis intermediates + GRU state
  half4* xb1h = (half4*)alloc((size_t)N*128*2);   // basis(H0) T1 cache
  half4* xb2h = (half4*)alloc((size_t)N*128*2);   // basis(H0) T2 cache
  half4* th1h = (half4*)alloc((size_t)N*128*2);   // scratch T1 (row-major)
  half4* HRbh = (half4*)alloc((size_t)N*128*2);   // CHUNK-major [4][N][32]
  half4* H0h  = (half4*)alloc((size_t)N*128*2);   // GRU state layer 0
  half4* H1h  = (half4*)alloc((size_t)N*128*2);   // GRU state layer 1
  half4* th2h = (half4*)alloc((size_t)N*128*2);   // scratch T2
  // fp16 MFMA weight fragments
  _Float16* bx8w  = (_Float16*)alloc(3072*2);
  _Float16* bx32w = (_Float16*)alloc(9216*2);
  _Float16* bh0w  = (_Float16*)alloc(6144*2);
  _Float16* bh1w  = (_Float16*)alloc(6144*2);
  // row32/col32 only live during prep, before Zh's first use -> alias into Zh
  // (E*8 = 8MB <= N*128*2 = 12.8MB)
  int* row32 = (int*)Zh;
  int* col32 = row32 + E;

  // ---- zero-init (ws is poisoned 0xAA before each call) ----
  (void)hipMemsetAsync(flag,   0, 4, stream);
  (void)hipMemsetAsync(deg,    0, (size_t)N*4, stream);
  (void)hipMemsetAsync(cnt,    0, (size_t)N*4, stream);
  (void)hipMemsetAsync(cnt2,   0, (size_t)N*4, stream);
  (void)hipMemsetAsync(H0h,    0, (size_t)N*128*2, stream);
  (void)hipMemsetAsync(H1h,    0, (size_t)N*128*2, stream);
  (void)hipMemsetAsync(xb1h,   0, (size_t)N*128*2, stream);  // basis(H0=0)=0 at t=0
  (void)hipMemsetAsync(xb2h,   0, (size_t)N*128*2, stream);
  (void)hipMemsetAsync(mixsum, 0, 512, stream);

  // ---- preprocessing: dtype detect, degrees, padded CSR build ----
  {
    int ndw = 4096;
    if (ndw > 2*E) ndw = 2*E;
    int nthread = ndw/2 + 1;
    detect_kernel<<<(nthread+255)/256, 256, 0, stream>>>((const unsigned*)eidx, ndw, flag);
  }
  convert_kernel<<<(E+255)/256, 256, 0, stream>>>(eidx, ew, E, flag, row32, col32, deg, cnt);
  node_prep_kernel<<<(N+255)/256, 256, 0, stream>>>(deg, dinv, dgv, N);
  scan_kernel<<<1, 1024, 0, stream>>>(cnt, ptrv, N);
  fill_kernel<<<(E+255)/256, 256, 0, stream>>>(row32, col32, ew, dinv, ptrv, cnt2,
                                               csr_src, csr_val, E);
  pad_kernel<<<(N+255)/256, 256, 0, stream>>>(cnt, ptrv, csr_src, csr_val, N);
  prep_weights_kernel<<<1, 256, 0, stream>>>(Wx0, Wx1, Wh0, Wh1, bx8w, bx32w, bh0w, bh1w);

  const int g128 = (N+7)/8;        // dual / gateB: 8 nodes / 256 threads
  const int nb32 = (N+31)/32;      // 32-node blocks
  const int hb   = (nb32+1)/2;     // per-XCD-pair block count
  const int g32a = 8*nb32;         // spmm32x one-slab-per-XCD
  const int g32b = 8*hb;           // spmm32x / spmm128c pair-pinned
  const int ntiles = (M + 15) >> 4;
  const int gMF = 512;             // 2048 waves

  // ---- L0 x-basis for ALL timesteps, XCD-pinned slabs ----
  {
    dim3 gT((N*32+255)/256, 12);
    transpose_all_kernel<<<gT, 256, 0, stream>>>(in0, xa0, N);
    // T1 = L x
    spmm32x_kernel<<<g32a,256,0,stream>>>(ptrv,csr_src,csr_val,dgv,
                                          (const half4*)xa0, nullptr,
                                          (half4*)xa1, N, 1.f, 0.f, 0, 0);
    spmm32x_kernel<<<g32b,256,0,stream>>>(ptrv,csr_src,csr_val,dgv,
                                          (const half4*)xa0, nullptr,
                                          (half4*)xa1, N, 1.f, 0.f, 8, 1);
    // T2 = 2 L T1 - x
    spmm32x_kernel<<<g32a,256,0,stream>>>(ptrv,csr_src,csr_val,dgv,
                                          (const half4*)xa1, (const half4*)xa0,
                                          (half4*)xa2, N, 2.f, -1.f, 0, 0);
    spmm32x_kernel<<<g32b,256,0,stream>>>(ptrv,csr_src,csr_val,dgv,
                                          (const half4*)xa1, (const half4*)xa0,
                                          (half4*)xa2, N, 2.f, -1.f, 8, 1);
  }

  for (int t = 0; t < 12; ++t){
    const _Float16* x0t = xa0 + (size_t)t*N*32;
    const _Float16* x1t = xa1 + (size_t)t*N*32;
    const _Float16* x2t = xa2 + (size_t)t*N*32;
    // ===== layer 0 (Fin=8); h-basis from cache (H0h, xb1h, xb2h) =====
    gateA_mfma_kernel<8><<<gMF,256,0,stream>>>(x0t,x1t,x2t,
                                               (const _Float16*)H0h,(const _Float16*)xb1h,
                                               (const _Float16*)xb2h,
                                               bx8w,bx0, bh0w,bh0,
                                               (_Float16*)Zh,(_Float16*)gx2h,
                                               (_Float16*)HRbh, M, N, ntiles);
    spmm128c_kernel<<<g32b,256,0,stream>>>(ptrv,csr_src,csr_val,dgv, HRbh, th1h, N);
    spmm_gateB_kernel<<<g128,256,0,stream>>>(ptrv,csr_src,csr_val,dgv, th1h, HRbh,
                                             Wh0+6144, bh0+64, Zh,gx2h, H0h, N);

    // ===== layer 1 (Fin=32, x = H0); basis(H0) -> cache (xb1h, xb2h) =====
    spmm_dual_kernel<<<g128,256,0,stream>>>(ptrv,csr_src,csr_val,dgv,
                                            H0h, H1h, nullptr, nullptr,
                                            xb1h, th1h, N, 1.f, 0.f);
    spmm_dual_kernel<<<g128,256,0,stream>>>(ptrv,csr_src,csr_val,dgv,
                                            xb1h, th1h, H0h, H1h,
                                            xb2h, th2h, N, 2.f, -1.f);
    gateA_mfma_kernel<32><<<gMF,256,0,stream>>>((const _Float16*)H0h,(const _Float16*)xb1h,
                                                (const _Float16*)xb2h,
                                                (const _Float16*)H1h,(const _Float16*)th1h,
                                                (const _Float16*)th2h,
                                                bx32w,bx1, bh1w,bh1,
                                                (_Float16*)Zh,(_Float16*)gx2h,
                                                (_Float16*)HRbh, M, N, ntiles);
    spmm128c_kernel<<<g32b,256,0,stream>>>(ptrv,csr_src,csr_val,dgv, HRbh, th1h, N);
    spmm_gateB_kernel<<<g128,256,0,stream>>>(ptrv,csr_src,csr_val,dgv, th1h, HRbh,
                                             Wh1+6144, bh1+64, Zh,gx2h, H1h, N);
  }

  // ---- readout ----
  readout_kernel<<<(4*N+255)/256, 256, 0, stream>>>((const _Float16*)H1h,
                                                    muW, mub, sgW, sgb, outp, N);
  mean_kernel<<<256, 128, 0, stream>>>((const _Float16*)H1h, mixsum, N);
  softmax_kernel<<<1, 128, 0, stream>>>(mixsum, outp + (size_t)16*N, 1.0f/(float)N);
}

// Round 8
// 5336.462 us; speedup vs baseline: 1.0129x; 1.0129x over previous
//
#include <hip/hip_runtime.h>
#include <cstdint>
#include <cstddef>

// ---------------------------------------------------------------------------
// GConvGRU (ChebConv K=3, 2 layers) + readout, for MI355X.
// R15 (8.2->6.8ms): gateA -> MFMA register GEMM.
// R16 (6.8->6.0ms): basis intermediates fp16-only; dual-gather spmm.
// R17 (6.0->5.5ms): all side-streams fp16.
// R18 (~neutral): L0 x-basis hoisted+batched; 12 concurrent slabs thrashed
//   per-XCD L2.
// R19 (5.49->5.37): GRU H state fp16-only. absmax bit-pinned at 0.0039.
// R20 (5.37->5.41, REGRESSION): bundled (a) spmm32x XCD-pinning [helped:
//   119us rows left top-5] + (b) spmm128c chunk-major HR gathers [hurt:
//   4x edge-list re-read + 4x shfl/addr VALU + 64B vs 256B gathers].
// R21 (this): revert (b) -> spmm128h row-major (R19-identical arithmetic),
//   keep (a) spmm32x pinning. Clean isolation of the spmm32x delta.
//   Predicted: ~5.28-5.32ms; absmax exactly 0.00390625. If neutral vs R19,
//   the gather floor is reached (within ~15% of random-gather LLC ceiling).
// ---------------------------------------------------------------------------

typedef _Float16 half4 __attribute__((ext_vector_type(4)));
typedef _Float16 half8_t __attribute__((ext_vector_type(8)));
typedef float f32x4 __attribute__((ext_vector_type(4)));

__device__ __forceinline__ float sigmoidf_(float x){ return 1.f/(1.f+__expf(-x)); }

// ---------------- preprocessing ----------------

__global__ void detect_kernel(const unsigned* __restrict__ buf, int ndw, int* flag){
  int i = blockIdx.x*blockDim.x + threadIdx.x;
  int j = 2*i + 1;
  if (j < ndw && buf[j] != 0u) atomicOr(flag, 1);   // flag=1 -> int32
}

__global__ void convert_kernel(const void* __restrict__ eidx, const float* __restrict__ w,
                               int E, const int* __restrict__ flag,
                               int* __restrict__ row32, int* __restrict__ col32,
                               float* __restrict__ deg, int* __restrict__ cnt){
  int e = blockIdx.x*blockDim.x + threadIdx.x;
  if (e >= E) return;
  int r, c;
  if (*flag){ const int* p = (const int*)eidx; r = p[e]; c = p[E+e]; }
  else { const long long* p = (const long long*)eidx; r = (int)p[e]; c = (int)p[(size_t)E+e]; }
  row32[e] = r; col32[e] = c;
  atomicAdd(deg + r, w[e]);
  atomicAdd(cnt + c, 1);
}

__global__ void node_prep_kernel(const float* __restrict__ deg, float* __restrict__ dinv,
                                 float* __restrict__ dg, int N){
  int n = blockIdx.x*blockDim.x + threadIdx.x;
  if (n >= N) return;
  float d = deg[n];
  if (d > 0.f){ dinv[n] = rsqrtf(d); dg[n] = 0.f; }
  else        { dinv[n] = 0.f;       dg[n] = -1.f; }
}

// Exclusive scan of PADDED counts ((cnt+7)&~7) -> ptr[N+1]. 1 block, 1024 thr.
__global__ void scan_kernel(const int* __restrict__ cnt, int* __restrict__ ptrout, int N){
  __shared__ int s[1024];
  int t = threadIdx.x;
  int chunk = (N + 1023) / 1024;
  int a0 = t*chunk, a1 = min(N, a0 + chunk);
  int sum = 0;
  for (int i = a0; i < a1; ++i) sum += (cnt[i]+7)&~7;
  s[t] = sum; __syncthreads();
  for (int off = 1; off < 1024; off <<= 1){
    int v = (t >= off) ? s[t-off] : 0;
    __syncthreads();
    s[t] += v;
    __syncthreads();
  }
  int run = (t == 0) ? 0 : s[t-1];
  for (int i = a0; i < a1; ++i){ ptrout[i] = run; run += (cnt[i]+7)&~7; }
  if (t == 1023) ptrout[N] = s[1023];
}

__global__ void fill_kernel(const int* __restrict__ row32, const int* __restrict__ col32,
                            const float* __restrict__ w, const float* __restrict__ dinv,
                            const int* __restrict__ ptrv, int* __restrict__ cnt2,
                            int* __restrict__ srcs, float* __restrict__ vals, int E){
  int e = blockIdx.x*blockDim.x + threadIdx.x;
  if (e >= E) return;
  int r = row32[e], c = col32[e];
  int p = ptrv[c] + atomicAdd(cnt2 + c, 1);
  srcs[p] = r;
  vals[p] = -w[e] * dinv[r] * dinv[c];
}

// Pad slots gather (src=0, val=0): bit-identical arithmetic, L2-hot row.
__global__ void pad_kernel(const int* __restrict__ cnt, const int* __restrict__ ptrv,
                           int* __restrict__ srcs, float* __restrict__ vals, int N){
  int n = blockIdx.x*blockDim.x + threadIdx.x;
  if (n >= N) return;
  int base = ptrv[n];
  int real = cnt[n];
  int padded = ptrv[n+1] - base;
  for (int j = real; j < padded; ++j){ srcs[base+j] = 0; vals[base+j] = 0.f; }
}

// ---------------- SpMM F=128, fp16 in -> fp16 out, alpha=1, no z -----------
__global__ __launch_bounds__(256) void spmm128h_kernel(
    const int* __restrict__ ptrv, const int* __restrict__ srcs, const float* __restrict__ vals,
    const float* __restrict__ dg, const half4* __restrict__ xh,
    half4* __restrict__ yh, int N){
  int t = threadIdx.x;
  int g = t >> 5, lane = t & 31;
  int node = blockIdx.x*8 + g;
  if (node >= N) return;
  int e0 = ptrv[node], e1 = ptrv[node+1];
  float4 acc = make_float4(0.f,0.f,0.f,0.f);
  for (int eb = e0; eb < e1; eb += 8){
    int j = eb + (lane & 7);
    int s = srcs[j]; float v = vals[j];
    #pragma unroll
    for (int q = 0; q < 8; ++q){
      int   sq = __shfl(s, q, 32);
      float vq = __shfl(v, q, 32);
      half4 hv = xh[(size_t)sq*32 + lane];
      acc.x = fmaf(vq, (float)hv.x, acc.x);
      acc.y = fmaf(vq, (float)hv.y, acc.y);
      acc.z = fmaf(vq, (float)hv.z, acc.z);
      acc.w = fmaf(vq, (float)hv.w, acc.w);
    }
  }
  size_t ii = (size_t)node*32 + lane;
  float dgn = dg[node];
  half4 xi = xh[ii];
  half4 hr;
  hr.x = (_Float16)(acc.x + dgn*(float)xi.x);
  hr.y = (_Float16)(acc.y + dgn*(float)xi.y);
  hr.z = (_Float16)(acc.z + dgn*(float)xi.z);
  hr.w = (_Float16)(acc.w + dgn*(float)xi.w);
  yh[ii] = hr;
}

// ---------------- dual SpMM F=128: two tables, one edge-list read ----------
// ya = a*(A xa + diag*xa) + b*za ; same for b-side. za/zb fp16 (may be null).
__global__ __launch_bounds__(256) void spmm_dual_kernel(
    const int* __restrict__ ptrv, const int* __restrict__ srcs, const float* __restrict__ vals,
    const float* __restrict__ dg,
    const half4* __restrict__ xa, const half4* __restrict__ xb,
    const half4* __restrict__ za, const half4* __restrict__ zb,
    half4* __restrict__ ya, half4* __restrict__ yb, int N, float alpha, float beta){
  int t = threadIdx.x;
  int g = t >> 5, lane = t & 31;
  int node = blockIdx.x*8 + g;
  if (node >= N) return;
  int e0 = ptrv[node], e1 = ptrv[node+1];
  float4 aa = make_float4(0.f,0.f,0.f,0.f);
  float4 ab = make_float4(0.f,0.f,0.f,0.f);
  for (int eb = e0; eb < e1; eb += 8){
    int j = eb + (lane & 7);
    int s = srcs[j]; float v = vals[j];
    #pragma unroll
    for (int q = 0; q < 8; ++q){
      int   sq = __shfl(s, q, 32);
      float vq = __shfl(v, q, 32);
      half4 ha = xa[(size_t)sq*32 + lane];
      half4 hb = xb[(size_t)sq*32 + lane];
      aa.x = fmaf(vq, (float)ha.x, aa.x);
      aa.y = fmaf(vq, (float)ha.y, aa.y);
      aa.z = fmaf(vq, (float)ha.z, aa.z);
      aa.w = fmaf(vq, (float)ha.w, aa.w);
      ab.x = fmaf(vq, (float)hb.x, ab.x);
      ab.y = fmaf(vq, (float)hb.y, ab.y);
      ab.z = fmaf(vq, (float)hb.z, ab.z);
      ab.w = fmaf(vq, (float)hb.w, ab.w);
    }
  }
  size_t ii = (size_t)node*32 + lane;
  float dgn = dg[node];
  half4 xia = xa[ii], xib = xb[ii];
  float4 ra, rb;
  ra.x = alpha*(aa.x + dgn*(float)xia.x);
  ra.y = alpha*(aa.y + dgn*(float)xia.y);
  ra.z = alpha*(aa.z + dgn*(float)xia.z);
  ra.w = alpha*(aa.w + dgn*(float)xia.w);
  rb.x = alpha*(ab.x + dgn*(float)xib.x);
  rb.y = alpha*(ab.y + dgn*(float)xib.y);
  rb.z = alpha*(ab.z + dgn*(float)xib.z);
  rb.w = alpha*(ab.w + dgn*(float)xib.w);
  if (za){
    half4 zva = za[ii];
    half4 zvb = zb[ii];
    ra.x = fmaf(beta, (float)zva.x, ra.x); ra.y = fmaf(beta, (float)zva.y, ra.y);
    ra.z = fmaf(beta, (float)zva.z, ra.z); ra.w = fmaf(beta, (float)zva.w, ra.w);
    rb.x = fmaf(beta, (float)zvb.x, rb.x); rb.y = fmaf(beta, (float)zvb.y, rb.y);
    rb.z = fmaf(beta, (float)zvb.z, rb.z); rb.w = fmaf(beta, (float)zvb.w, rb.w);
  }
  half4 hra, hrb;
  hra.x = (_Float16)ra.x; hra.y = (_Float16)ra.y; hra.z = (_Float16)ra.z; hra.w = (_Float16)ra.w;
  hrb.x = (_Float16)rb.x; hrb.y = (_Float16)rb.y; hrb.z = (_Float16)rb.z; hrb.w = (_Float16)rb.w;
  ya[ii] = hra;
  yb[ii] = hrb;
}

// ---------------- SpMM F=32, fp16, XCD-PINNED slabs -----------------------
// two_per_xcd=0: slabs slab0..slab0+7, one per XCD (id%8).
// two_per_xcd=1: slabs slab0..slab0+3, one per XCD pair.
__global__ __launch_bounds__(256) void spmm32x_kernel(
    const int* __restrict__ ptrv, const int* __restrict__ srcs, const float* __restrict__ vals,
    const float* __restrict__ dg, const half4* __restrict__ xh, const half4* __restrict__ z,
    half4* __restrict__ yh, int N, float alpha, float beta,
    int slab0, int two_per_xcd){
  int i = blockIdx.x;
  int xcd = i & 7;
  int slab, j;
  if (two_per_xcd){ slab = slab0 + (xcd >> 1); j = (i >> 3)*2 + (xcd & 1); }
  else            { slab = slab0 + xcd;        j = i >> 3; }
  size_t soff = (size_t)slab * N * 8;   // half4 units per slab
  const half4* xs = xh + soff;
  half4*       ys = yh + soff;
  int t = threadIdx.x;
  int g = t >> 3, lane = t & 7;
  int node = j*32 + g;
  if (node >= N) return;
  int e0 = ptrv[node], e1 = ptrv[node+1];
  float4 acc = make_float4(0.f,0.f,0.f,0.f);
  for (int eb = e0; eb < e1; eb += 8){
    int jj = eb + lane;
    int s = srcs[jj]; float v = vals[jj];
    #pragma unroll
    for (int q = 0; q < 8; ++q){
      int   sq = __shfl(s, q, 8);
      float vq = __shfl(v, q, 8);
      half4 hv = xs[(size_t)sq*8 + lane];
      acc.x = fmaf(vq, (float)hv.x, acc.x);
      acc.y = fmaf(vq, (float)hv.y, acc.y);
      acc.z = fmaf(vq, (float)hv.z, acc.z);
      acc.w = fmaf(vq, (float)hv.w, acc.w);
    }
  }
  size_t ii = (size_t)node*8 + lane;
  float dgn = dg[node];
  half4 xi = xs[ii];
  float4 r;
  r.x = alpha*(acc.x + dgn*(float)xi.x);
  r.y = alpha*(acc.y + dgn*(float)xi.y);
  r.z = alpha*(acc.z + dgn*(float)xi.z);
  r.w = alpha*(acc.w + dgn*(float)xi.w);
  if (z){
    half4 zi = (z + soff)[ii];
    r.x = fmaf(beta, (float)zi.x, r.x);
    r.y = fmaf(beta, (float)zi.y, r.y);
    r.z = fmaf(beta, (float)zi.z, r.z);
    r.w = fmaf(beta, (float)zi.w, r.w);
  }
  half4 hr;
  hr.x = (_Float16)r.x; hr.y = (_Float16)r.y; hr.z = (_Float16)r.z; hr.w = (_Float16)r.w;
  ys[ii] = hr;
}

// ---------------- fused: th2 = 2*(L th1) - HRb  +  gateB GRU update --------
// All streams fp16 including GRU state (read+write Hh in place).
__global__ __launch_bounds__(256) void spmm_gateB_kernel(
    const int* __restrict__ ptrv, const int* __restrict__ srcs, const float* __restrict__ vals,
    const float* __restrict__ dg, const half4* __restrict__ th1h,
    const half4* __restrict__ HRbh,
    const float* __restrict__ Whh, const float* __restrict__ bhh,
    const half4* __restrict__ Zh, const half4* __restrict__ gx2h,
    half4* __restrict__ Hh, int N){
  __shared__ _Float16 sp[8][3][128];
  __shared__ float sW[3072];
  int t = threadIdx.x;
  int g = t >> 5, lane = t & 31;
  int node = blockIdx.x*8 + g;
  bool valid = (node < N);
  if (!valid) node = N-1;
  for (int idx = t; idx < 3072; idx += 256) sW[idx] = Whh[idx];
  size_t ii = (size_t)node*32 + lane;
  half4 Zvh  = Zh[ii];
  half4 Gxh  = gx2h[ii];
  half4 Holdh = Hh[ii];
  half4 zih  = HRbh[ii];
  int e0 = ptrv[node], e1 = ptrv[node+1];
  float4 acc = make_float4(0.f,0.f,0.f,0.f);
  for (int eb = e0; eb < e1; eb += 8){
    int j = eb + (lane & 7);
    int s = srcs[j]; float v = vals[j];
    #pragma unroll
    for (int q = 0; q < 8; ++q){
      int   sq = __shfl(s, q, 32);
      float vq = __shfl(v, q, 32);
      half4 hv = th1h[(size_t)sq*32 + lane];
      acc.x = fmaf(vq, (float)hv.x, acc.x);
      acc.y = fmaf(vq, (float)hv.y, acc.y);
      acc.z = fmaf(vq, (float)hv.z, acc.z);
      acc.w = fmaf(vq, (float)hv.w, acc.w);
    }
  }
  float dgn = dg[node];
  half4 xih = th1h[ii];
  half4 p2h;
  p2h.x = (_Float16)(2.f*(acc.x + dgn*(float)xih.x) - (float)zih.x);
  p2h.y = (_Float16)(2.f*(acc.y + dgn*(float)xih.y) - (float)zih.y);
  p2h.z = (_Float16)(2.f*(acc.z + dgn*(float)xih.z) - (float)zih.z);
  p2h.w = (_Float16)(2.f*(acc.w + dgn*(float)xih.w) - (float)zih.w);
  ((half4*)&sp[g][0][0])[lane] = zih;
  ((half4*)&sp[g][1][0])[lane] = xih;
  ((half4*)&sp[g][2][0])[lane] = p2h;
  __syncthreads();
  const float4* W4 = (const float4*)sW;
  float4 bv = ((const float4*)bhh)[lane & 7];
  float gh0 = bv.x, gh1 = bv.y, gh2 = bv.z, gh3 = bv.w;
  #pragma unroll 1
  for (int k = 0; k < 3; ++k){
    const _Float16* pk = &sp[g][k][(lane >> 3)*32];
    #pragma unroll
    for (int o = 0; o < 32; o += 4){
      half4 pv = *reinterpret_cast<const half4*>(pk + o);
      #pragma unroll
      for (int oo = 0; oo < 4; ++oo){
        float p = (float)pv[oo];
        float4 wv = W4[k*256 + (o+oo)*8 + (lane & 7)];
        gh0 = fmaf(p, wv.x, gh0);
        gh1 = fmaf(p, wv.y, gh1);
        gh2 = fmaf(p, wv.z, gh2);
        gh3 = fmaf(p, wv.w, gh3);
      }
    }
  }
  if (valid){
    half4 hh;
    float Ht, Z;
    Z = (float)Zvh.x; Ht = tanhf((float)Gxh.x + gh0); hh.x = (_Float16)(Z*(float)Holdh.x + (1.f - Z)*Ht);
    Z = (float)Zvh.y; Ht = tanhf((float)Gxh.y + gh1); hh.y = (_Float16)(Z*(float)Holdh.y + (1.f - Z)*Ht);
    Z = (float)Zvh.z; Ht = tanhf((float)Gxh.z + gh2); hh.z = (_Float16)(Z*(float)Holdh.z + (1.f - Z)*Ht);
    Z = (float)Zvh.w; Ht = tanhf((float)Gxh.w + gh3); hh.w = (_Float16)(Z*(float)Holdh.w + (1.f - Z)*Ht);
    Hh[ii] = hh;
  }
}

// ---------------- transpose layer-0 input, ALL timesteps (-> fp16 slabs) ---
__global__ void transpose_all_kernel(const float* __restrict__ in, _Float16* __restrict__ out,
                                     int N){
  int idx = blockIdx.x*blockDim.x + threadIdx.x;   // over N*32
  int t = blockIdx.y;                               // timestep slab
  if (idx >= N*32) return;
  int n = idx >> 5; int r = idx & 31; int b = r >> 3; int i = r & 7;
  out[(size_t)t*N*32 + idx] = (_Float16)in[(((size_t)b*12 + t)*N + n)*8 + i];
}

// ---------------- gateA: MFMA GEMM -----------------------------------------
// Weight pack to f16 MFMA B-fragment layout (k = 8*(lane>>4)+j, col = lane&15,
// SAME mapping used when building A, so any HW k-permutation cancels).
__global__ void prep_weights_kernel(const float* __restrict__ Wx0, const float* __restrict__ Wx1,
                                    const float* __restrict__ Wh0, const float* __restrict__ Wh1,
                                    _Float16* __restrict__ bx8, _Float16* __restrict__ bx32,
                                    _Float16* __restrict__ bh0f, _Float16* __restrict__ bh1f){
  int t0 = threadIdx.x;
  for (int idx = t0; idx < 9216; idx += 256){
    int j = idx & 7; int l = (idx>>3)&63; int tc = idx>>9;     // tc = t*3+c
    int tt = tc/3, c = tc - 3*tt;
    int out = tt*16 + (l&15); int g = out>>5; int o = out&31;
    int fin = 8*(l>>4)+j;
    bx32[idx] = (_Float16)Wx1[(((g*3+c)*32+fin)<<5)+o];
  }
  for (int idx = t0; idx < 3072; idx += 256){
    int j = idx & 7; int l = (idx>>3)&63; int tt = idx>>9;
    int out = tt*16 + (l&15); int g = out>>5; int o = out&31;
    int b = l>>4;
    bx8[idx] = (b < 3) ? (_Float16)Wx0[(((g*3+b)*8+j)<<5)+o] : (_Float16)0.f;
  }
  for (int idx = t0; idx < 6144; idx += 256){
    int j = idx & 7; int l = (idx>>3)&63; int tc = idx>>9;     // tc = u*3+c, u<4
    int u = tc/3, c = tc - 3*u;
    int out = u*16 + (l&15); int g = out>>5; int o = out&31;
    int fin = 8*(l>>4)+j;
    bh0f[idx] = (_Float16)Wh0[(((g*3+c)*32+fin)<<5)+o];
    bh1f[idx] = (_Float16)Wh1[(((g*3+c)*32+fin)<<5)+o];
  }
}

// Per wave: one 16-row tile x 160 output cols (10 C tiles), grid-stride over
// tiles with B resident in VGPRs. All activation I/O fp16; HR epilogue uses
// the state shadow (h0h) directly.
template<int FIN>
__global__ __launch_bounds__(256) void gateA_mfma_kernel(
    const _Float16* __restrict__ x0h, const _Float16* __restrict__ x1h,
    const _Float16* __restrict__ x2h,                       // [M x FIN] halves
    const _Float16* __restrict__ h0h, const _Float16* __restrict__ h1h,
    const _Float16* __restrict__ h2h,                       // [M x 32] halves
    const _Float16* __restrict__ BX, const float* __restrict__ bx,
    const _Float16* __restrict__ BH, const float* __restrict__ bh,
    _Float16* __restrict__ Zh, _Float16* __restrict__ gx2h,
    _Float16* __restrict__ HRbh, int M, int ntiles){
  constexpr int NXC = (FIN == 32) ? 3 : 1;
  int t = threadIdx.x;
  int lane = t & 63, wv = t >> 6;
  int l15 = lane & 15, lhi = lane >> 4;

  half8_t Bxf[6*NXC], Bhf[12];
  {
    const half8_t* p = (const half8_t*)BX;
    #pragma unroll
    for (int i = 0; i < 6*NXC; ++i) Bxf[i] = p[i*64 + lane];
    const half8_t* q = (const half8_t*)BH;
    #pragma unroll
    for (int i = 0; i < 12; ++i) Bhf[i] = q[i*64 + lane];
  }
  float bz0 = bx[l15]    + bh[l15];
  float bz1 = bx[16+l15] + bh[16+l15];
  float br0 = bx[32+l15] + bh[32+l15];
  float br1 = bx[48+l15] + bh[48+l15];
  float b20 = bx[64+l15];
  float b21 = bx[80+l15];

  int wid = blockIdx.x*4 + wv;
  int nw  = gridDim.x*4;
  for (int tile = wid; tile < ntiles; tile += nw){
    int r0 = tile << 4;
    int rowa = r0 + l15; if (rowa >= M) rowa = M - 1;

    half8_t Ax[NXC], Ah[3];
    if constexpr (FIN == 32){
      const _Float16* xm[3] = {x0h, x1h, x2h};
      #pragma unroll
      for (int c = 0; c < 3; ++c)
        Ax[c] = *reinterpret_cast<const half8_t*>(xm[c] + (size_t)rowa*32 + 8*lhi);
    } else {
      if (lhi < 3){
        const _Float16* p = (lhi == 0) ? x0h : (lhi == 1) ? x1h : x2h;
        Ax[0] = *reinterpret_cast<const half8_t*>(p + (size_t)rowa*8);
      } else {
        #pragma unroll
        for (int j = 0; j < 8; ++j) Ax[0][j] = (_Float16)0.f;
      }
    }
    {
      const _Float16* hm[3] = {h0h, h1h, h2h};
      #pragma unroll
      for (int c = 0; c < 3; ++c)
        Ah[c] = *reinterpret_cast<const half8_t*>(hm[c] + (size_t)rowa*32 + 8*lhi);
    }

    f32x4 zv = {0.f, 0.f, 0.f, 0.f};
    f32x4 CX[6], CH[4];
    #pragma unroll
    for (int i = 0; i < 6; ++i) CX[i] = zv;
    #pragma unroll
    for (int i = 0; i < 4; ++i) CH[i] = zv;

    #pragma unroll
    for (int tt = 0; tt < 6; ++tt){
      #pragma unroll
      for (int c = 0; c < NXC; ++c)
        CX[tt] = __builtin_amdgcn_mfma_f32_16x16x32_f16(Ax[c], Bxf[tt*NXC+c], CX[tt], 0, 0, 0);
    }
    #pragma unroll
    for (int u = 0; u < 4; ++u){
      #pragma unroll
      for (int c = 0; c < 3; ++c)
        CH[u] = __builtin_amdgcn_mfma_f32_16x16x32_f16(Ah[c], Bhf[u*3+c], CH[u], 0, 0, 0);
    }

    // C/D layout: col = lane&15, row = 4*(lane>>4)+reg  [m89-verified]
    #pragma unroll
    for (int reg = 0; reg < 4; ++reg){
      int row = r0 + lhi*4 + reg;
      if (row < M){
        size_t i0 = (size_t)row*32 + l15;
        size_t i1 = i0 + 16;
        float Z0 = sigmoidf_(CX[0][reg] + CH[0][reg] + bz0);
        float Z1 = sigmoidf_(CX[1][reg] + CH[1][reg] + bz1);
        float R0 = sigmoidf_(CX[2][reg] + CH[2][reg] + br0);
        float R1 = sigmoidf_(CX[3][reg] + CH[3][reg] + br1);
        Zh[i0] = (_Float16)Z0; Zh[i1] = (_Float16)Z1;
        gx2h[i0] = (_Float16)(CX[4][reg] + b20);
        gx2h[i1] = (_Float16)(CX[5][reg] + b21);
        float hv0 = (float)h0h[i0]*R0, hv1 = (float)h0h[i1]*R1;
        HRbh[i0] = (_Float16)hv0; HRbh[i1] = (_Float16)hv1;
      }
    }
  }
}

// ---------------- readout (fp16 H1) ----------------
__global__ void readout_kernel(const _Float16* __restrict__ H1, const float* __restrict__ muW,
                               const float* __restrict__ mub, const float* __restrict__ sgW,
                               const float* __restrict__ sgb, float* __restrict__ outp, int N){
  int idx = blockIdx.x*blockDim.x + threadIdx.x;   // over 4*N
  if (idx >= 4*N) return;
  int b = idx / N, n = idx - b*N;
  const _Float16* h = H1 + (size_t)n*128 + b*32;
  float m0 = mub[0], m1 = mub[1], s0 = sgb[0], s1 = sgb[1];
  #pragma unroll
  for (int o = 0; o < 32; ++o){
    float v = (float)h[o];
    m0 = fmaf(v, muW[o*2+0], m0);
    m1 = fmaf(v, muW[o*2+1], m1);
    s0 = fmaf(v, sgW[o*2+0], s0);
    s1 = fmaf(v, sgW[o*2+1], s1);
  }
  size_t base = (size_t)(b*N + n)*2;
  outp[base]   = sigmoidf_(m0);
  outp[base+1] = sigmoidf_(m1);
  size_t sb = (size_t)8*N + base;
  outp[sb]   = (s0 > 15.f) ? s0 : log1pf(__expf(s0));
  outp[sb+1] = (s1 > 15.f) ? s1 : log1pf(__expf(s1));
}

__global__ void mean_kernel(const _Float16* __restrict__ H1, float* __restrict__ mixsum, int N){
  int t = threadIdx.x;   // 128 = (b,o)
  int chunk = (N + gridDim.x - 1) / gridDim.x;
  int n0 = blockIdx.x*chunk, n1 = min(N, n0 + chunk);
  float acc = 0.f;
  for (int n = n0; n < n1; ++n) acc += (float)H1[(size_t)n*128 + t];
  atomicAdd(mixsum + t, acc);
}

__global__ void softmax_kernel(const float* __restrict__ mixsum, float* __restrict__ outp,
                               float invN){
  __shared__ float v[128];
  __shared__ float e[128];
  int t = threadIdx.x; int b = t >> 5;
  float m = mixsum[t]*invN;
  v[t] = m; __syncthreads();
  float mx = -1e30f;
  for (int o = 0; o < 32; ++o) mx = fmaxf(mx, v[b*32 + o]);
  float ex = __expf(m - mx);
  e[t] = ex; __syncthreads();
  float s = 0.f;
  for (int o = 0; o < 32; ++o) s += e[b*32 + o];
  outp[t] = ex / s;
}

// ---------------------------------------------------------------------------

extern "C" void kernel_launch(void* const* d_in, const int* in_sizes, int n_in,
                              void* d_out, int out_size, void* d_ws, size_t ws_size,
                              hipStream_t stream){
  const float* in0  = (const float*)d_in[0];
  const void*  eidx = d_in[1];
  const float* ew   = (const float*)d_in[2];
  const float* Wx0  = (const float*)d_in[3];
  const float* Wh0  = (const float*)d_in[4];
  const float* bx0  = (const float*)d_in[5];
  const float* bh0  = (const float*)d_in[6];
  const float* Wx1  = (const float*)d_in[7];
  const float* Wh1  = (const float*)d_in[8];
  const float* bx1  = (const float*)d_in[9];
  const float* bh1  = (const float*)d_in[10];
  const float* muW  = (const float*)d_in[11];
  const float* mub  = (const float*)d_in[12];
  const float* sgW  = (const float*)d_in[13];
  const float* sgb  = (const float*)d_in[14];
  float* outp = (float*)d_out;

  const int N = in_sizes[0] / (4*12*8);
  const int E = in_sizes[1] / 2;
  const int M = 4*N;
  const int EP = E + 8*N;        // padded-edge capacity

  // ---- carve workspace ----
  char* w = (char*)d_ws;
  size_t off = 0;
  auto alloc = [&](size_t bytes)->void*{
    void* p = w + off;
    off += (bytes + 255) & ~(size_t)255;
    return p;
  };
  int*   csr_src = (int*)  alloc((size_t)EP*4);
  float* csr_val = (float*)alloc((size_t)EP*4);
  int*   ptrv    = (int*)  alloc((size_t)(N+1)*4);
  int*   cnt     = (int*)  alloc((size_t)N*4);
  int*   cnt2    = (int*)  alloc((size_t)N*4);
  float* deg     = (float*)alloc((size_t)N*4);
  float* dinv    = (float*)alloc((size_t)N*4);
  float* dgv     = (float*)alloc((size_t)N*4);
  int*   flag    = (int*)  alloc(256);
  float* mixsum  = (float*)alloc(512);
  // fp16 gate buffers
  half4* Zh   = (half4*)alloc((size_t)N*128*2);
  half4* gx2h = (half4*)alloc((size_t)N*128*2);
  // fp16 L0 x-basis, batched over all 12 timesteps: [t][node][32] halves
  _Float16* xa0 = (_Float16*)alloc((size_t)12*N*32*2);
  _Float16* xa1 = (_Float16*)alloc((size_t)12*N*32*2);
  _Float16* xa2 = (_Float16*)alloc((size_t)12*N*32*2);
  // fp16 basis intermediates + GRU state (fp16-only)
  half4* xb1h = (half4*)alloc((size_t)N*128*2);   // basis(H0) T1 cache
  half4* xb2h = (half4*)alloc((size_t)N*128*2);   // basis(H0) T2 cache
  half4* th1h = (half4*)alloc((size_t)N*128*2);   // scratch T1
  half4* th2h = (half4*)alloc((size_t)N*128*2);   // scratch T2
  half4* HRbh = (half4*)alloc((size_t)N*128*2);
  half4* H0h  = (half4*)alloc((size_t)N*128*2);   // GRU state layer 0
  half4* H1h  = (half4*)alloc((size_t)N*128*2);   // GRU state layer 1
  // fp16 MFMA weight fragments
  _Float16* bx8w  = (_Float16*)alloc(3072*2);
  _Float16* bx32w = (_Float16*)alloc(9216*2);
  _Float16* bh0w  = (_Float16*)alloc(6144*2);
  _Float16* bh1w  = (_Float16*)alloc(6144*2);
  // row32/col32 only live during prep, before Zh's first use -> alias into Zh
  // (E*8 = 8MB <= N*128*2 = 12.8MB)
  int* row32 = (int*)Zh;
  int* col32 = row32 + E;

  // ---- zero-init (ws is poisoned 0xAA before each call) ----
  (void)hipMemsetAsync(flag,   0, 4, stream);
  (void)hipMemsetAsync(deg,    0, (size_t)N*4, stream);
  (void)hipMemsetAsync(cnt,    0, (size_t)N*4, stream);
  (void)hipMemsetAsync(cnt2,   0, (size_t)N*4, stream);
  (void)hipMemsetAsync(H0h,    0, (size_t)N*128*2, stream);
  (void)hipMemsetAsync(H1h,    0, (size_t)N*128*2, stream);
  (void)hipMemsetAsync(xb1h,   0, (size_t)N*128*2, stream);  // basis(H0=0)=0 at t=0
  (void)hipMemsetAsync(xb2h,   0, (size_t)N*128*2, stream);
  (void)hipMemsetAsync(mixsum, 0, 512, stream);

  // ---- preprocessing: dtype detect, degrees, padded CSR build ----
  {
    int ndw = 4096;
    if (ndw > 2*E) ndw = 2*E;
    int nthread = ndw/2 + 1;
    detect_kernel<<<(nthread+255)/256, 256, 0, stream>>>((const unsigned*)eidx, ndw, flag);
  }
  convert_kernel<<<(E+255)/256, 256, 0, stream>>>(eidx, ew, E, flag, row32, col32, deg, cnt);
  node_prep_kernel<<<(N+255)/256, 256, 0, stream>>>(deg, dinv, dgv, N);
  scan_kernel<<<1, 1024, 0, stream>>>(cnt, ptrv, N);
  fill_kernel<<<(E+255)/256, 256, 0, stream>>>(row32, col32, ew, dinv, ptrv, cnt2,
                                               csr_src, csr_val, E);
  pad_kernel<<<(N+255)/256, 256, 0, stream>>>(cnt, ptrv, csr_src, csr_val, N);
  prep_weights_kernel<<<1, 256, 0, stream>>>(Wx0, Wx1, Wh0, Wh1, bx8w, bx32w, bh0w, bh1w);

  const int g128 = (N+7)/8;        // spmm128h / dual / gateB: 8 nodes / 256 threads
  const int nb32 = (N+31)/32;      // 32-node blocks
  const int hb   = (nb32+1)/2;     // per-XCD-pair block count
  const int g32a = 8*nb32;         // spmm32x one-slab-per-XCD
  const int g32b = 8*hb;           // spmm32x pair-pinned
  const int ntiles = (M + 15) >> 4;
  const int gMF = 512;             // 2048 waves

  // ---- L0 x-basis for ALL timesteps, XCD-pinned slabs ----
  {
    dim3 gT((N*32+255)/256, 12);
    transpose_all_kernel<<<gT, 256, 0, stream>>>(in0, xa0, N);
    // T1 = L x
    spmm32x_kernel<<<g32a,256,0,stream>>>(ptrv,csr_src,csr_val,dgv,
                                          (const half4*)xa0, nullptr,
                                          (half4*)xa1, N, 1.f, 0.f, 0, 0);
    spmm32x_kernel<<<g32b,256,0,stream>>>(ptrv,csr_src,csr_val,dgv,
                                          (const half4*)xa0, nullptr,
                                          (half4*)xa1, N, 1.f, 0.f, 8, 1);
    // T2 = 2 L T1 - x
    spmm32x_kernel<<<g32a,256,0,stream>>>(ptrv,csr_src,csr_val,dgv,
                                          (const half4*)xa1, (const half4*)xa0,
                                          (half4*)xa2, N, 2.f, -1.f, 0, 0);
    spmm32x_kernel<<<g32b,256,0,stream>>>(ptrv,csr_src,csr_val,dgv,
                                          (const half4*)xa1, (const half4*)xa0,
                                          (half4*)xa2, N, 2.f, -1.f, 8, 1);
  }

  for (int t = 0; t < 12; ++t){
    const _Float16* x0t = xa0 + (size_t)t*N*32;
    const _Float16* x1t = xa1 + (size_t)t*N*32;
    const _Float16* x2t = xa2 + (size_t)t*N*32;
    // ===== layer 0 (Fin=8); h-basis from cache (H0h, xb1h, xb2h) =====
    gateA_mfma_kernel<8><<<gMF,256,0,stream>>>(x0t,x1t,x2t,
                                               (const _Float16*)H0h,(const _Float16*)xb1h,
                                               (const _Float16*)xb2h,
                                               bx8w,bx0, bh0w,bh0,
                                               (_Float16*)Zh,(_Float16*)gx2h,
                                               (_Float16*)HRbh, M, ntiles);
    spmm128h_kernel<<<g128,256,0,stream>>>(ptrv,csr_src,csr_val,dgv, HRbh, th1h, N);
    spmm_gateB_kernel<<<g128,256,0,stream>>>(ptrv,csr_src,csr_val,dgv, th1h, HRbh,
                                             Wh0+6144, bh0+64, Zh,gx2h, H0h, N);

    // ===== layer 1 (Fin=32, x = H0); basis(H0) -> cache (xb1h, xb2h) =====
    spmm_dual_kernel<<<g128,256,0,stream>>>(ptrv,csr_src,csr_val,dgv,
                                            H0h, H1h, nullptr, nullptr,
                                            xb1h, th1h, N, 1.f, 0.f);
    spmm_dual_kernel<<<g128,256,0,stream>>>(ptrv,csr_src,csr_val,dgv,
                                            xb1h, th1h, H0h, H1h,
                                            xb2h, th2h, N, 2.f, -1.f);
    gateA_mfma_kernel<32><<<gMF,256,0,stream>>>((const _Float16*)H0h,(const _Float16*)xb1h,
                                                (const _Float16*)xb2h,
                                                (const _Float16*)H1h,(const _Float16*)th1h,
                                                (const _Float16*)th2h,
                                                bx32w,bx1, bh1w,bh1,
                                                (_Float16*)Zh,(_Float16*)gx2h,
                                                (_Float16*)HRbh, M, ntiles);
    spmm128h_kernel<<<g128,256,0,stream>>>(ptrv,csr_src,csr_val,dgv, HRbh, th1h, N);
    spmm_gateB_kernel<<<g128,256,0,stream>>>(ptrv,csr_src,csr_val,dgv, th1h, HRbh,
                                             Wh1+6144, bh1+64, Zh,gx2h, H1h, N);
  }

  // ---- readout ----
  readout_kernel<<<(4*N+255)/256, 256, 0, stream>>>((const _Float16*)H1h,
                                                    muW, mub, sgW, sgb, outp, N);
  mean_kernel<<<256, 128, 0, stream>>>((const _Float16*)H1h, mixsum, N);
  softmax_kernel<<<1, 128, 0, stream>>>(mixsum, outp + (size_t)16*N, 1.0f/(float)N);
}